// Round 1
// baseline (165.826 us; speedup 1.0000x reference)
//
#include <hip/hip_runtime.h>

// ActivationDelta: out = where(ACT_MASK[col] & (v != 0), clamp(v + delta, 0, 1), v)
// ACT columns (FEAT_DIM=2133): {0, 81, 165+3j : j in [0,40)}  (42 columns)

#define FEAT_DIM 2133u

__device__ __forceinline__ bool is_act_col(unsigned c) {
    // unsigned wrap: c < 165 -> (c-165) is huge -> range check fails
    unsigned d = c - 165u;
    return (c == 0u) | (c == 81u) | ((d <= 117u) & (d % 3u == 0u));
}

__global__ void __launch_bounds__(256)
ActivationDelta_19318762897441_kernel(const float* __restrict__ in,
                                      const float* __restrict__ dptr,
                                      float* __restrict__ out,
                                      unsigned n4, unsigned n)
{
    const float dlt = dptr[0];
    const unsigned stride = gridDim.x * blockDim.x;
    const unsigned tid = blockIdx.x * blockDim.x + threadIdx.x;

    const float4* __restrict__ in4  = reinterpret_cast<const float4*>(in);
    float4* __restrict__ out4       = reinterpret_cast<float4*>(out);

    for (unsigned i = tid; i < n4; i += stride) {
        float4 v = in4[i];
        unsigned c0 = (i * 4u) % FEAT_DIM;
        float r[4] = {v.x, v.y, v.z, v.w};
#pragma unroll
        for (int k = 0; k < 4; ++k) {
            unsigned c = c0 + (unsigned)k;
            c = (c >= FEAT_DIM) ? (c - FEAT_DIM) : c;
            float x = r[k];
            float b = fminf(fmaxf(x + dlt, 0.0f), 1.0f);
            bool ap = is_act_col(c) & (x != 0.0f);
            r[k] = ap ? b : x;
        }
        out4[i] = make_float4(r[0], r[1], r[2], r[3]);
    }

    // scalar tail (n % 4 elements; n = 50000*2133 is divisible by 4, but be safe)
    for (unsigned i = n4 * 4u + tid; i < n; i += stride) {
        unsigned c = i % FEAT_DIM;
        float x = in[i];
        float b = fminf(fmaxf(x + dlt, 0.0f), 1.0f);
        bool ap = is_act_col(c) & (x != 0.0f);
        out[i] = ap ? b : x;
    }
}

extern "C" void kernel_launch(void* const* d_in, const int* in_sizes, int n_in,
                              void* d_out, int out_size, void* d_ws, size_t ws_size,
                              hipStream_t stream) {
    const float* in   = (const float*)d_in[0];
    const float* dlt  = (const float*)d_in[1];
    float* out        = (float*)d_out;

    const unsigned n  = (unsigned)in_sizes[0];
    const unsigned n4 = n / 4u;

    const int block = 256;
    unsigned want = (n4 + block - 1) / block;
    unsigned grid = want < 2048u ? (want ? want : 1u) : 2048u;

    ActivationDelta_19318762897441_kernel<<<dim3(grid), dim3(block), 0, stream>>>(
        in, dlt, out, n4, n);
}